// Round 3
// baseline (6775.422 us; speedup 1.0000x reference)
//
#include <hip/hip_runtime.h>

typedef unsigned int u32;
typedef unsigned short u16;
typedef short bf16x8 __attribute__((ext_vector_type(8)));
typedef u16 u16x8 __attribute__((ext_vector_type(8)));
typedef float f32x4 __attribute__((ext_vector_type(4)));
typedef _Float16 h2v __attribute__((ext_vector_type(2)));

#define HID 256
#define NCLS 64
#define GATES 1024
#define SEQ 512
#define NBATCH 256
#define FEAT 512
#define INDIM 576

// ---------- helpers ----------
__device__ __forceinline__ u16 f2b(float f) {              // fp32 -> bf16 RNE
  u32 u = __builtin_bit_cast(u32, f);
  u += 0x7fffu + ((u >> 16) & 1u);
  return (u16)(u >> 16);
}
__device__ __forceinline__ float b2f(u16 v) {
  u32 u = ((u32)v) << 16;
  return __builtin_bit_cast(float, u);
}
__device__ __forceinline__ u32 packh2(float a, float b) {  // two fp32 -> packed f16x2
  u16 lo = __builtin_bit_cast(u16, (_Float16)a);
  u16 hi = __builtin_bit_cast(u16, (_Float16)b);
  return (u32)lo | ((u32)hi << 16);
}
__device__ __forceinline__ float fdot2a(u32 h, u32 w, float c) {
#if __has_builtin(__builtin_amdgcn_fdot2)
  return __builtin_amdgcn_fdot2(__builtin_bit_cast(h2v, h),
                                __builtin_bit_cast(h2v, w), c, false);
#else
  h2v a = __builtin_bit_cast(h2v, h);
  h2v b = __builtin_bit_cast(h2v, w);
  return c + (float)a[0] * (float)b[0] + (float)a[1] * (float)b[1];
#endif
}
__device__ __forceinline__ float sigmf_(float x) { return 1.f / (1.f + __expf(-x)); }
__device__ __forceinline__ float tanhf_(float x) { return 1.f - 2.f / (1.f + __expf(2.f * x)); }

// ---------- kernel 0: weight prep + out zero ----------
// lstm_seq thread map (1024 threads): kq = tid>>8 (K-quarter), gl = tid&255,
// owns 4 gates {gl + j*256, j<4}, K range [kq*64, kq*64+64).
// WhhF  : u32 [32][1024][4]  ALL of W_hh as register frags (512 KB).
//         frag i = j*8+qq: component q = f16x2 pair (W_hh[g][k], W_hh[g][k+1]),
//         g = gl + j*256, k = kq*64 + qq*8 + 2q.
// WoutR : u32 [8][1024]      thread t: cls=t&63, kq16=t>>6; wo[i] = pair at
//         k0 = kq16*16 + 2i.
// Woh2  : f32 [64][256][4]   Woh2[p][c][jj] = W_ih[(jj*256+c)*576 + 512+p].
__global__ void prep_kernel(const float* __restrict__ W_ih, const float* __restrict__ W_hh,
                            const float* __restrict__ W_out,
                            u16* __restrict__ Wihk, u32* __restrict__ WhhF,
                            u32* __restrict__ WoutR, float* __restrict__ Woh2,
                            float* __restrict__ out) {
  int idx = blockIdx.x * 256 + threadIdx.x;
  const int N0 = 1024 * 512;            // Wihk
  const int N1 = N0 + 32 * 1024 * 4;    // WhhF (131072 u32 = 512 KB)
  const int N2 = N1 + 8 * 1024;         // WoutR
  const int N3 = N2 + 64 * 256 * 4;     // Woh2
  if (idx < N0) {
    int g = idx >> 9, k = idx & 511;
    Wihk[idx] = f2b(W_ih[g * INDIM + k]);
  } else if (idx < N1) {
    int r = idx - N0;
    int q = r & 3, u4 = r >> 2;            // u4 in [0, 32768)
    int t = u4 & 1023, i = u4 >> 10;       // i in [0, 32)
    int j = i >> 3, qq = i & 7;
    int kqv = t >> 8, glv = t & 255;
    int g = glv + j * 256;
    int k = kqv * 64 + qq * 8 + 2 * q;
    WhhF[r] = packh2(W_hh[g * HID + k], W_hh[g * HID + k + 1]);
  } else if (idx < N2) {
    int r = idx - N1;                      // [0, 8192)
    int i = r >> 10, t = r & 1023;
    int cls = t & 63, kq16 = t >> 6;
    int k0 = kq16 * 16 + 2 * i;
    WoutR[r] = packh2(W_out[cls * HID + k0], W_out[cls * HID + k0 + 1]);
  } else if (idx < N3) {
    int r = idx - N2;
    int jj = r & 3, c = (r >> 2) & 255, p = r >> 10;
    Woh2[r] = W_ih[(jj * 256 + c) * INDIM + FEAT + p];
  } else if (idx == N3) {
    out[0] = 0.f;
  }
}

// ---------- kernel 1: Xp = bf16( x @ W_ih[:, :512]^T + b_ih + b_hh ) ----------
// Cell-major store: gate g at (g&255)*4 + (g>>8) -> cell thread reads ushort4 (i,f,g,o).
__global__ __launch_bounds__(256) void gemm_xp(const float* __restrict__ x,
                                               const u16* __restrict__ Wihk,
                                               const float* __restrict__ b_ih,
                                               const float* __restrict__ b_hh,
                                               u16* __restrict__ Xp) {
  __shared__ u16 As[128 * 32];
  __shared__ u16 Bs[128 * 32];
  const int tid = threadIdx.x;
  const int bx = blockIdx.x;
  const int m0 = (bx >> 3) * 128;
  const int n0 = (bx & 7) * 128;
  const int wave = tid >> 6, lane = tid & 63;
  const int wm = (wave >> 1) * 64, wn = (wave & 1) * 64;
  const int l16 = lane & 15, quad = lane >> 4;
  const int r = tid >> 2;
  const int c8 = (tid & 3) * 8;

  f32x4 zero4 = {0.f, 0.f, 0.f, 0.f};
  f32x4 acc[4][4];
#pragma unroll
  for (int i = 0; i < 4; ++i)
#pragma unroll
    for (int j = 0; j < 4; ++j) acc[i][j] = zero4;

  for (int k0 = 0; k0 < FEAT; k0 += 32) {
#pragma unroll
    for (int p = 0; p < 2; ++p) {
      const float* src = x + (size_t)(m0 + r + p * 64) * FEAT + k0 + c8;
      float4 f0 = *(const float4*)src;
      float4 f1 = *(const float4*)(src + 4);
      u16x8 v;
      v[0] = f2b(f0.x); v[1] = f2b(f0.y); v[2] = f2b(f0.z); v[3] = f2b(f0.w);
      v[4] = f2b(f1.x); v[5] = f2b(f1.y); v[6] = f2b(f1.z); v[7] = f2b(f1.w);
      *(u16x8*)&As[(r + p * 64) * 32 + c8] = v;
    }
#pragma unroll
    for (int p = 0; p < 2; ++p) {
      *(uint4*)&Bs[(r + p * 64) * 32 + c8] =
          *(const uint4*)&Wihk[(size_t)(n0 + r + p * 64) * FEAT + k0 + c8];
    }
    __syncthreads();
    bf16x8 am[4], bn[4];
#pragma unroll
    for (int i = 0; i < 4; ++i)
      am[i] = *(const bf16x8*)&As[(wm + i * 16 + l16) * 32 + quad * 8];
#pragma unroll
    for (int j = 0; j < 4; ++j)
      bn[j] = *(const bf16x8*)&Bs[(wn + j * 16 + l16) * 32 + quad * 8];
#pragma unroll
    for (int i = 0; i < 4; ++i)
#pragma unroll
      for (int j = 0; j < 4; ++j)
        acc[i][j] = __builtin_amdgcn_mfma_f32_16x16x32_bf16(am[i], bn[j], acc[i][j], 0, 0, 0);
    __syncthreads();
  }

  float bias[4];
  int cols[4];
#pragma unroll
  for (int j = 0; j < 4; ++j) {
    cols[j] = n0 + wn + j * 16 + l16;
    bias[j] = b_ih[cols[j]] + b_hh[cols[j]];
  }
#pragma unroll
  for (int i = 0; i < 4; ++i) {
    int rowb = m0 + wm + i * 16 + quad * 4;
#pragma unroll
    for (int j = 0; j < 4; ++j) {
      int pcol = ((cols[j] & 255) << 2) + (cols[j] >> 8);
#pragma unroll
      for (int rr = 0; rr < 4; ++rr) {
        Xp[(size_t)(rowb + rr) * GATES + pcol] = f2b(acc[i][j][rr] + bias[j]);
      }
    }
  }
}

// ---------- kernel 2: persistent recurrent decoder ----------
// 256 blocks (1 batch row) x 1024 threads (16 waves, 4/SIMD).
// Thread t: kq = t>>8, gl = t&255 -> 4 gates {gl+j*256} x K-quarter.
// ALL W_hh in VGPRs (wr[32] uint4 = 128 regs); zero LDS weight traffic.
// Round-1-proven 4-barrier pipeline: A matvec -> B reduce+cell -> C1 logits
// -> C2 argmax(w0)||loss(w1).
__global__ __launch_bounds__(1024, 4) void lstm_seq(
    const u16* __restrict__ Xp, const uint4* __restrict__ WhhF,
    const u32* __restrict__ WoutR, const float4* __restrict__ Woh2,
    const float* __restrict__ b_out, const int* __restrict__ tag,
    float* __restrict__ out) {
  __shared__ float pA[4096];     // partials [kq][j*256 + gl]
  __shared__ u32 h_u32[128];     // h packed f16 pairs
  __shared__ float pbuf[1024];   // logit partials [kq16*64 + cls]
  __shared__ int tag_l[512];
  __shared__ int predv;

  const int tid = threadIdx.x;
  const int b = blockIdx.x;
  const int kq = tid >> 8;       // wave-uniform
  const int gl = tid & 255;

  // ---- init: full W_hh into registers ----
  uint4 wr[32];
#pragma unroll
  for (int i = 0; i < 32; ++i) wr[i] = WhhF[i * 1024 + tid];
  u32 wo[8];
#pragma unroll
  for (int i = 0; i < 8; ++i) wo[i] = WoutR[i * 1024 + tid];
  if (tid < 512) tag_l[tid] = tag[b * SEQ + tid];
  if (tid < 128) h_u32[tid] = 0u;
  if (tid == 0) predv = 0;
  float c_reg = 0.f;
  float bout_c = b_out[tid & 63];
  float loss_acc = 0.f;
  const u16* xp_row = Xp + (size_t)b * SEQ * GATES;
  ushort4 xc = make_ushort4(0, 0, 0, 0);
  if (tid < 256) xc = *(const ushort4*)(xp_row + tid * 4);
  __syncthreads();

#pragma unroll 1
  for (int s = 0; s < SEQ; ++s) {
    // ---- loop top (cell threads): pred-dependent Woh + Xp(s+1) prefetch ----
    float4 woh = make_float4(0.f, 0.f, 0.f, 0.f);
    ushort4 xn = xc;
    if (tid < 256) {
      int pred = predv;
      woh = Woh2[pred * 256 + tid];
      int sn = (s + 1 < SEQ) ? s + 1 : s;
      xn = *(const ushort4*)(xp_row + (size_t)sn * GATES + tid * 4);
    }

    // ---- phase A: matvec, weights all in regs, h broadcast from LDS ----
    float a0 = 0.f, a1 = 0.f, a2 = 0.f, a3 = 0.f;
#pragma unroll
    for (int qq = 0; qq < 8; ++qq) {
      uint4 h4 = *(const uint4*)(h_u32 + kq * 32 + qq * 4);  // wave-broadcast
      uint4 w0 = wr[qq];
      uint4 w1 = wr[8 + qq];
      uint4 w2 = wr[16 + qq];
      uint4 w3 = wr[24 + qq];
      a0 = fdot2a(h4.x, w0.x, a0);
      a0 = fdot2a(h4.y, w0.y, a0);
      a0 = fdot2a(h4.z, w0.z, a0);
      a0 = fdot2a(h4.w, w0.w, a0);
      a1 = fdot2a(h4.x, w1.x, a1);
      a1 = fdot2a(h4.y, w1.y, a1);
      a1 = fdot2a(h4.z, w1.z, a1);
      a1 = fdot2a(h4.w, w1.w, a1);
      a2 = fdot2a(h4.x, w2.x, a2);
      a2 = fdot2a(h4.y, w2.y, a2);
      a2 = fdot2a(h4.z, w2.z, a2);
      a2 = fdot2a(h4.w, w2.w, a2);
      a3 = fdot2a(h4.x, w3.x, a3);
      a3 = fdot2a(h4.y, w3.y, a3);
      a3 = fdot2a(h4.z, w3.z, a3);
      a3 = fdot2a(h4.w, w3.w, a3);
    }
    pA[kq * 1024 + gl]       = a0;
    pA[kq * 1024 + 256 + gl] = a1;
    pA[kq * 1024 + 512 + gl] = a2;
    pA[kq * 1024 + 768 + gl] = a3;
    __syncthreads();

    // ---- phase B: K-partial reduce + LSTM cell (threads 0..255) ----
    if (tid < 256) {
      float ig = pA[tid]       + pA[1024 + tid] + pA[2048 + tid] + pA[3072 + tid]
               + b2f(xc.x) + woh.x;
      float fg = pA[256 + tid] + pA[1280 + tid] + pA[2304 + tid] + pA[3328 + tid]
               + b2f(xc.y) + woh.y;
      float gg = pA[512 + tid] + pA[1536 + tid] + pA[2560 + tid] + pA[3584 + tid]
               + b2f(xc.z) + woh.z;
      float og = pA[768 + tid] + pA[1792 + tid] + pA[2816 + tid] + pA[3840 + tid]
               + b2f(xc.w) + woh.w;
      float iv = sigmf_(ig), fv = sigmf_(fg), gv = tanhf_(gg), ov = sigmf_(og);
      c_reg = fv * c_reg + iv * gv;
      float h = ov * tanhf_(c_reg);
      ((u16*)h_u32)[tid] = __builtin_bit_cast(u16, (_Float16)h);
    }
    __syncthreads();

    // ---- phase C1: logit partials, thread -> (cls = tid&63, kq16 = tid>>6) ----
    {
      int kq16 = tid >> 6;   // wave-uniform
      uint4 ha = *(const uint4*)(h_u32 + kq16 * 8);
      uint4 hb = *(const uint4*)(h_u32 + kq16 * 8 + 4);
      float p = 0.f;
      p = fdot2a(ha.x, wo[0], p);
      p = fdot2a(ha.y, wo[1], p);
      p = fdot2a(ha.z, wo[2], p);
      p = fdot2a(ha.w, wo[3], p);
      p = fdot2a(hb.x, wo[4], p);
      p = fdot2a(hb.y, wo[5], p);
      p = fdot2a(hb.z, wo[6], p);
      p = fdot2a(hb.w, wo[7], p);
      pbuf[tid] = p;
    }
    xc = xn;
    __syncthreads();

    // ---- phase C2: wave0 argmax -> predv ; wave1 log-softmax + NLL ----
    if (tid < 128) {
      int l6 = tid & 63;
      float lg = bout_c;
#pragma unroll
      for (int k = 0; k < 16; ++k) lg += pbuf[k * 64 + l6];
      if (tid < 64) {
        float v = lg; int ii = l6;
#pragma unroll
        for (int off = 32; off; off >>= 1) {
          float ov = __shfl_xor(v, off);
          int oi = __shfl_xor(ii, off);
          if (ov > v || (ov == v && oi < ii)) { v = ov; ii = oi; }
        }
        if (tid == 0) predv = ii;
      } else {
        float v = lg;
#pragma unroll
        for (int off = 32; off; off >>= 1) v = fmaxf(v, __shfl_xor(v, off));
        float ssum = __expf(lg - v);
#pragma unroll
        for (int off = 32; off; off >>= 1) ssum += __shfl_xor(ssum, off);
        int t = tag_l[s];
        float lt = __shfl(lg, t & 63);
        if (t >= 0) loss_acc += v + __logf(ssum) - lt;
      }
    }
    __syncthreads();   // predv/pbuf stable for next iteration
  }
  if (tid == 64) atomicAdd(out, loss_acc);
}

// ---------- launcher ----------
extern "C" void kernel_launch(void* const* d_in, const int* in_sizes, int n_in,
                              void* d_out, int out_size, void* d_ws, size_t ws_size,
                              hipStream_t stream) {
  const float* x     = (const float*)d_in[0];
  const int*   tag   = (const int*)d_in[1];
  const float* W_ih  = (const float*)d_in[2];
  const float* W_hh  = (const float*)d_in[3];
  const float* b_ih  = (const float*)d_in[4];
  const float* b_hh  = (const float*)d_in[5];
  const float* W_out = (const float*)d_in[6];
  const float* b_out = (const float*)d_in[7];
  float* out = (float*)d_out;

  char* w = (char*)d_ws;
  // ws layout (bytes):
  //   Xp    @ 0          : 268,435,456
  //   Wihk  @ 268435456  :   1,048,576
  //   WhhF  @ 269484032  :     524,288   (absorbs old WhhL2 region)
  //   WoutR @ 270008320  :      32,768
  //   Woh2  @ 270041088  :     262,144
  u16* Xp      = (u16*)w;
  u16* Wihk    = (u16*)(w + 268435456ull);
  u32* WhhF    = (u32*)(w + 269484032ull);
  u32* WoutR   = (u32*)(w + 270008320ull);
  float* Woh2  = (float*)(w + 270041088ull);

  prep_kernel<<<2849, 256, 0, stream>>>(W_ih, W_hh, W_out, Wihk, WhhF, WoutR, Woh2, out);
  gemm_xp<<<8192, 256, 0, stream>>>(x, Wihk, b_ih, b_hh, Xp);
  lstm_seq<<<256, 1024, 0, stream>>>(Xp, (const uint4*)WhhF, WoutR,
                                     (const float4*)Woh2, b_out, tag, out);
}

// Round 4
// 2211.258 us; speedup vs baseline: 3.0641x; 3.0641x over previous
//
#include <hip/hip_runtime.h>

typedef unsigned int u32;
typedef unsigned short u16;
typedef short bf16x8 __attribute__((ext_vector_type(8)));
typedef u16 u16x8 __attribute__((ext_vector_type(8)));
typedef float f32x4 __attribute__((ext_vector_type(4)));
typedef _Float16 h2v __attribute__((ext_vector_type(2)));

#define HID 256
#define NCLS 64
#define GATES 1024
#define SEQ 512
#define NBATCH 256
#define FEAT 512
#define INDIM 576

// ---------- helpers ----------
__device__ __forceinline__ u16 f2b(float f) {              // fp32 -> bf16 RNE
  u32 u = __builtin_bit_cast(u32, f);
  u += 0x7fffu + ((u >> 16) & 1u);
  return (u16)(u >> 16);
}
__device__ __forceinline__ float b2f(u16 v) {
  u32 u = ((u32)v) << 16;
  return __builtin_bit_cast(float, u);
}
__device__ __forceinline__ u32 packh2(float a, float b) {  // two fp32 -> packed f16x2
  u16 lo = __builtin_bit_cast(u16, (_Float16)a);
  u16 hi = __builtin_bit_cast(u16, (_Float16)b);
  return (u32)lo | ((u32)hi << 16);
}
__device__ __forceinline__ float fdot2a(u32 h, u32 w, float c) {
#if __has_builtin(__builtin_amdgcn_fdot2)
  return __builtin_amdgcn_fdot2(__builtin_bit_cast(h2v, h),
                                __builtin_bit_cast(h2v, w), c, false);
#else
  h2v a = __builtin_bit_cast(h2v, h);
  h2v b = __builtin_bit_cast(h2v, w);
  return c + (float)a[0] * (float)b[0] + (float)a[1] * (float)b[1];
#endif
}
__device__ __forceinline__ float sigmf_(float x) { return 1.f / (1.f + __expf(-x)); }
__device__ __forceinline__ float tanhf_(float x) { return 1.f - 2.f / (1.f + __expf(2.f * x)); }

// ---------- kernel 0: weight prep + out zero ----------
// lstm_seq thread map (512 thr): kq = tid>>7, gl = tid&127, 8 gates gl+j*128.
// WhhF  : u32 [48][512][4] register frags, i = j*8+qq, j in [0,6):
//         component q = f16x2 pair (W_hh[g][k], W_hh[g][k+1]),
//         g = gl + j*128, k = kq*64 + qq*8 + 2q.
// WhhL2 : u32 [16][512][4] LDS frags, i2 = (j-6)*8+qq, j in {6,7}, same formula.
// WoutR : u32 [16][512]    cls = t&63, kq8 = t>>6; pair at k0 = kq8*32 + 2j.
// Woh2  : f32 [64][256][4] Woh2[p][c][jj] = W_ih[(jj*256+c)*576 + 512+p].
__global__ void prep_kernel(const float* __restrict__ W_ih, const float* __restrict__ W_hh,
                            const float* __restrict__ W_out,
                            u16* __restrict__ Wihk, u32* __restrict__ WhhF,
                            u32* __restrict__ WhhL2, u32* __restrict__ WoutR,
                            float* __restrict__ Woh2, float* __restrict__ out) {
  int idx = blockIdx.x * 256 + threadIdx.x;
  const int N0 = 1024 * 512;            // Wihk
  const int N1 = N0 + 48 * 512 * 4;     // WhhF
  const int N2 = N1 + 16 * 512 * 4;     // WhhL2
  const int N3 = N2 + 16 * 512;         // WoutR
  const int N4 = N3 + 64 * 256 * 4;     // Woh2
  if (idx < N0) {
    int g = idx >> 9, k = idx & 511;
    Wihk[idx] = f2b(W_ih[g * INDIM + k]);
  } else if (idx < N1) {
    int r = idx - N0;
    int q = r & 3, u4 = r >> 2;
    int t = u4 & 511, i = u4 >> 9;          // i in [0,48)
    int j = i >> 3, qq = i & 7;
    int kqv = t >> 7, glv = t & 127;
    int g = glv + j * 128;
    int k = kqv * 64 + qq * 8 + 2 * q;
    WhhF[r] = packh2(W_hh[g * HID + k], W_hh[g * HID + k + 1]);
  } else if (idx < N2) {
    int r = idx - N1;
    int q = r & 3, u4 = r >> 2;
    int t = u4 & 511, i2 = u4 >> 9;         // i2 in [0,16)
    int j = 6 + (i2 >> 3), qq = i2 & 7;
    int kqv = t >> 7, glv = t & 127;
    int g = glv + j * 128;
    int k = kqv * 64 + qq * 8 + 2 * q;
    WhhL2[r] = packh2(W_hh[g * HID + k], W_hh[g * HID + k + 1]);
  } else if (idx < N3) {
    int r = idx - N2;
    int j = r >> 9, t = r & 511;
    int cc = t & 63, kqv = t >> 6;
    int k0 = kqv * 32 + 2 * j;
    WoutR[r] = packh2(W_out[cc * HID + k0], W_out[cc * HID + k0 + 1]);
  } else if (idx < N4) {
    int r = idx - N3;
    int jj = r & 3, c = (r >> 2) & 255, p = r >> 10;
    Woh2[r] = W_ih[(jj * 256 + c) * INDIM + FEAT + p];
  } else if (idx == N4) {
    out[0] = 0.f;
  }
}

// ---------- kernel 1: Xp = bf16( x @ W_ih[:, :512]^T + b_ih + b_hh ) ----------
// Cell-major store: gate g at (g&255)*4 + (g>>8) -> cell thread reads ushort4 (i,f,g,o).
__global__ __launch_bounds__(256) void gemm_xp(const float* __restrict__ x,
                                               const u16* __restrict__ Wihk,
                                               const float* __restrict__ b_ih,
                                               const float* __restrict__ b_hh,
                                               u16* __restrict__ Xp) {
  __shared__ u16 As[128 * 32];
  __shared__ u16 Bs[128 * 32];
  const int tid = threadIdx.x;
  const int bx = blockIdx.x;
  const int m0 = (bx >> 3) * 128;
  const int n0 = (bx & 7) * 128;
  const int wave = tid >> 6, lane = tid & 63;
  const int wm = (wave >> 1) * 64, wn = (wave & 1) * 64;
  const int l16 = lane & 15, quad = lane >> 4;
  const int r = tid >> 2;
  const int c8 = (tid & 3) * 8;

  f32x4 zero4 = {0.f, 0.f, 0.f, 0.f};
  f32x4 acc[4][4];
#pragma unroll
  for (int i = 0; i < 4; ++i)
#pragma unroll
    for (int j = 0; j < 4; ++j) acc[i][j] = zero4;

  for (int k0 = 0; k0 < FEAT; k0 += 32) {
#pragma unroll
    for (int p = 0; p < 2; ++p) {
      const float* src = x + (size_t)(m0 + r + p * 64) * FEAT + k0 + c8;
      float4 f0 = *(const float4*)src;
      float4 f1 = *(const float4*)(src + 4);
      u16x8 v;
      v[0] = f2b(f0.x); v[1] = f2b(f0.y); v[2] = f2b(f0.z); v[3] = f2b(f0.w);
      v[4] = f2b(f1.x); v[5] = f2b(f1.y); v[6] = f2b(f1.z); v[7] = f2b(f1.w);
      *(u16x8*)&As[(r + p * 64) * 32 + c8] = v;
    }
#pragma unroll
    for (int p = 0; p < 2; ++p) {
      *(uint4*)&Bs[(r + p * 64) * 32 + c8] =
          *(const uint4*)&Wihk[(size_t)(n0 + r + p * 64) * FEAT + k0 + c8];
    }
    __syncthreads();
    bf16x8 am[4], bn[4];
#pragma unroll
    for (int i = 0; i < 4; ++i)
      am[i] = *(const bf16x8*)&As[(wm + i * 16 + l16) * 32 + quad * 8];
#pragma unroll
    for (int j = 0; j < 4; ++j)
      bn[j] = *(const bf16x8*)&Bs[(wn + j * 16 + l16) * 32 + quad * 8];
#pragma unroll
    for (int i = 0; i < 4; ++i)
#pragma unroll
      for (int j = 0; j < 4; ++j)
        acc[i][j] = __builtin_amdgcn_mfma_f32_16x16x32_bf16(am[i], bn[j], acc[i][j], 0, 0, 0);
    __syncthreads();
  }

  float bias[4];
  int cols[4];
#pragma unroll
  for (int j = 0; j < 4; ++j) {
    cols[j] = n0 + wn + j * 16 + l16;
    bias[j] = b_ih[cols[j]] + b_hh[cols[j]];
  }
#pragma unroll
  for (int i = 0; i < 4; ++i) {
    int rowb = m0 + wm + i * 16 + quad * 4;
#pragma unroll
    for (int j = 0; j < 4; ++j) {
      int pcol = ((cols[j] & 255) << 2) + (cols[j] >> 8);
#pragma unroll
      for (int rr = 0; rr < 4; ++rr) {
        Xp[(size_t)(rowb + rr) * GATES + pcol] = f2b(acc[i][j][rr] + bias[j]);
      }
    }
  }
}

// ---------- kernel 2: persistent recurrent decoder, C2 overlapped with A ----------
// 256 blocks x 512 threads (2 waves/SIMD, the unique feasible occupancy point:
// W_hh 512KB = 384KB regs + 128KB LDS; reg file is 512KB/CU).
// Step: [top: wave0 argmax(s-1)->Woh stage, wave1 loss(s-1), all waves matvec A(s)]
//       bar [B: cell] bar [C1: logits] bar.  3 barriers; C2 chain hidden under A.
__global__ __launch_bounds__(512, 2) void lstm_seq(
    const u16* __restrict__ Xp, const uint4* __restrict__ WhhF,
    const uint4* __restrict__ WhhL2, const u32* __restrict__ WoutR,
    const float4* __restrict__ Woh2, const float* __restrict__ b_out,
    const int* __restrict__ tag, float* __restrict__ out) {
  extern __shared__ u32 smem[];
  uint4* whhl = (uint4*)smem;              // [0, 32768) u32 : 8192 uint4
  float* pA   = (float*)(smem + 32768);    // 4096 f32 : partials [kq][g]
  u32*  h_u32 = smem + 36864;              // 128 u32 (256 f16)
  float* pbuf = (float*)(smem + 36992);    // 512 f32 : logit partials
  int*  tag_l = (int*)(smem + 37504);      // 512 i32
  float4* wohv = (float4*)(smem + 38016);  // 256 float4 : staged Woh2[pred]

  const int tid = threadIdx.x;
  const int b = blockIdx.x;
  const int kq = tid >> 7;     // K-quarter (wave-uniform)
  const int gl = tid & 127;
  const int wave = tid >> 6;
  const int lane = tid & 63;

  // ---- init: weights into registers / LDS ----
  uint4 wr[48];
#pragma unroll
  for (int i = 0; i < 48; ++i) wr[i] = WhhF[i * 512 + tid];
  u32 wo[16];
#pragma unroll
  for (int i = 0; i < 16; ++i) wo[i] = WoutR[i * 512 + tid];
#pragma unroll
  for (int i = 0; i < 16; ++i) whhl[i * 512 + tid] = WhhL2[i * 512 + tid];
  tag_l[tid] = tag[b * SEQ + tid];
  if (tid < 128) h_u32[tid] = 0u;
  if (tid < 256) wohv[tid] = Woh2[tid];   // pred(-1) = 0 prefill
  float c_reg = 0.f;
  float bout_c = b_out[tid & 63];
  float loss_acc = 0.f;
  const u16* xp_row = Xp + (size_t)b * SEQ * GATES;
  ushort4 xc = make_ushort4(0, 0, 0, 0);
  if (tid < 256) xc = *(const ushort4*)(xp_row + tid * 4);
  __syncthreads();

  const uint4* wb0 = whhl + tid;          // + qq*512
  const uint4* wb1 = whhl + 4096 + tid;   // + qq*512  (j=7 slice)

#pragma unroll 1
  for (int s = 0; s < SEQ; ++s) {
    // ---- Xp(s+1) prefetch (cell threads) ----
    ushort4 xn = xc;
    if (tid < 256) {
      int sn = (s + 1 < SEQ) ? s + 1 : s;
      xn = *(const ushort4*)(xp_row + (size_t)sn * GATES + tid * 4);
    }

    // ---- overlapped C2(s-1): wave0 argmax + Woh stage; wave1 loss ----
    if (s > 0) {
      if (wave == 0) {
        float lg = bout_c;
#pragma unroll
        for (int k = 0; k < 8; ++k) lg += pbuf[k * 64 + lane];
        float v = lg; int ii = lane;
#pragma unroll
        for (int off = 32; off; off >>= 1) {
          float ov = __shfl_xor(v, off);
          int oi = __shfl_xor(ii, off);
          if (ov > v || (ov == v && oi < ii)) { v = ov; ii = oi; }
        }
        // stage Woh2[pred] into LDS (coalesced 4x1KB), consumed in B after bar
#pragma unroll
        for (int j = 0; j < 4; ++j) {
          wohv[lane + j * 64] = Woh2[ii * 256 + lane + j * 64];
        }
      } else if (wave == 1) {
        float lg = bout_c;
#pragma unroll
        for (int k = 0; k < 8; ++k) lg += pbuf[k * 64 + lane];
        float v = lg;
#pragma unroll
        for (int off = 32; off; off >>= 1) v = fmaxf(v, __shfl_xor(v, off));
        float ssum = __expf(lg - v);
#pragma unroll
        for (int off = 32; off; off >>= 1) ssum += __shfl_xor(ssum, off);
        int t = tag_l[s - 1];
        float lt = __shfl(lg, t & 63);
        if (t >= 0) loss_acc += v + __logf(ssum) - lt;
      }
    }

    // ---- phase A: matvec, K-quarter per thread, h staged in 2 batches ----
    float acc[8];
#pragma unroll
    for (int j = 0; j < 8; ++j) acc[j] = 0.f;
#pragma unroll
    for (int half = 0; half < 2; ++half) {
      uint4 hh[4];
#pragma unroll
      for (int q = 0; q < 4; ++q)
        hh[q] = *(const uint4*)(h_u32 + kq * 32 + (half * 4 + q) * 4);  // broadcast
#pragma unroll
      for (int q = 0; q < 4; ++q) {
        const int qq = half * 4 + q;
        uint4 w6 = wb0[qq * 512];
        uint4 w7 = wb1[qq * 512];
        u32 ha[4] = {hh[q].x, hh[q].y, hh[q].z, hh[q].w};
#pragma unroll
        for (int j = 0; j < 6; ++j) {
          uint4 wj = wr[j * 8 + qq];
          acc[j] = fdot2a(ha[0], wj.x, acc[j]);
          acc[j] = fdot2a(ha[1], wj.y, acc[j]);
          acc[j] = fdot2a(ha[2], wj.z, acc[j]);
          acc[j] = fdot2a(ha[3], wj.w, acc[j]);
        }
        acc[6] = fdot2a(ha[0], w6.x, acc[6]);
        acc[6] = fdot2a(ha[1], w6.y, acc[6]);
        acc[6] = fdot2a(ha[2], w6.z, acc[6]);
        acc[6] = fdot2a(ha[3], w6.w, acc[6]);
        acc[7] = fdot2a(ha[0], w7.x, acc[7]);
        acc[7] = fdot2a(ha[1], w7.y, acc[7]);
        acc[7] = fdot2a(ha[2], w7.z, acc[7]);
        acc[7] = fdot2a(ha[3], w7.w, acc[7]);
      }
    }
#pragma unroll
    for (int j = 0; j < 8; ++j) pA[kq * 1024 + gl + j * 128] = acc[j];
    __syncthreads();   // bar 1: pA + wohv ready

    // ---- phase B: K-partial reduce + LSTM cell (threads 0..255) ----
    if (tid < 256) {
      float4 woh = wohv[tid];
      float ig = pA[tid]       + pA[1024 + tid] + pA[2048 + tid] + pA[3072 + tid]
               + b2f(xc.x) + woh.x;
      float fg = pA[256 + tid] + pA[1280 + tid] + pA[2304 + tid] + pA[3328 + tid]
               + b2f(xc.y) + woh.y;
      float gg = pA[512 + tid] + pA[1536 + tid] + pA[2560 + tid] + pA[3584 + tid]
               + b2f(xc.z) + woh.z;
      float og = pA[768 + tid] + pA[1792 + tid] + pA[2816 + tid] + pA[3840 + tid]
               + b2f(xc.w) + woh.w;
      float iv = sigmf_(ig), fv = sigmf_(fg), gv = tanhf_(gg), ov = sigmf_(og);
      c_reg = fv * c_reg + iv * gv;
      float h = ov * tanhf_(c_reg);
      ((u16*)h_u32)[tid] = __builtin_bit_cast(u16, (_Float16)h);
    }
    __syncthreads();   // bar 2: h(s) ready

    // ---- phase C1: logit partials, thread -> (cls = tid&63, octant = tid>>6) ----
    {
      int kq8 = tid >> 6;   // wave-uniform
      float p = 0.f;
#pragma unroll
      for (int c = 0; c < 4; ++c) {
        uint4 h4 = *(const uint4*)(h_u32 + kq8 * 16 + c * 4);
        p = fdot2a(h4.x, wo[c * 4 + 0], p);
        p = fdot2a(h4.y, wo[c * 4 + 1], p);
        p = fdot2a(h4.z, wo[c * 4 + 2], p);
        p = fdot2a(h4.w, wo[c * 4 + 3], p);
      }
      pbuf[tid] = p;
    }
    xc = xn;
    __syncthreads();   // bar 3: pbuf(s) ready for next-iteration C2
  }

  // ---- epilogue: loss(511) ----
  if (wave == 1) {
    float lg = bout_c;
#pragma unroll
    for (int k = 0; k < 8; ++k) lg += pbuf[k * 64 + lane];
    float v = lg;
#pragma unroll
    for (int off = 32; off; off >>= 1) v = fmaxf(v, __shfl_xor(v, off));
    float ssum = __expf(lg - v);
#pragma unroll
    for (int off = 32; off; off >>= 1) ssum += __shfl_xor(ssum, off);
    int t = tag_l[SEQ - 1];
    float lt = __shfl(lg, t & 63);
    if (t >= 0) loss_acc += v + __logf(ssum) - lt;
    if (tid == 64) atomicAdd(out, loss_acc);
  }
}

// ---------- launcher ----------
extern "C" void kernel_launch(void* const* d_in, const int* in_sizes, int n_in,
                              void* d_out, int out_size, void* d_ws, size_t ws_size,
                              hipStream_t stream) {
  const float* x     = (const float*)d_in[0];
  const int*   tag   = (const int*)d_in[1];
  const float* W_ih  = (const float*)d_in[2];
  const float* W_hh  = (const float*)d_in[3];
  const float* b_ih  = (const float*)d_in[4];
  const float* b_hh  = (const float*)d_in[5];
  const float* W_out = (const float*)d_in[6];
  const float* b_out = (const float*)d_in[7];
  float* out = (float*)d_out;

  char* w = (char*)d_ws;
  // ws layout (bytes):
  //   Xp    @ 0          : 268,435,456
  //   Wihk  @ 268435456  :   1,048,576
  //   WhhF  @ 269484032  :     393,216
  //   WhhL2 @ 269877248  :     131,072
  //   WoutR @ 270008320  :      32,768
  //   Woh2  @ 270041088  :     262,144
  u16* Xp      = (u16*)w;
  u16* Wihk    = (u16*)(w + 268435456ull);
  u32* WhhF    = (u32*)(w + 269484032ull);
  u32* WhhL2   = (u32*)(w + 269877248ull);
  u32* WoutR   = (u32*)(w + 270008320ull);
  float* Woh2  = (float*)(w + 270041088ull);

  const int smem_bytes = 39040 * 4;  // 156,160 B dynamic LDS (<=160 KB/CU)
  (void)hipFuncSetAttribute((const void*)lstm_seq,
                            hipFuncAttributeMaxDynamicSharedMemorySize, smem_bytes);

  prep_kernel<<<2849, 256, 0, stream>>>(W_ih, W_hh, W_out, Wihk, WhhF, WhhL2, WoutR, Woh2, out);
  gemm_xp<<<8192, 256, 0, stream>>>(x, Wihk, b_ih, b_hh, Xp);
  lstm_seq<<<256, 512, smem_bytes, stream>>>(Xp, (const uint4*)WhhF, (const uint4*)WhhL2,
                                             WoutR, (const float4*)Woh2, b_out, tag, out);
}